// Round 3
// baseline (47396.075 us; speedup 1.0000x reference)
//
#include <hip/hip_runtime.h>

#define S_LEN   4096
#define R_DIM   512
#define N_BATCH 32
#define D_IN_   8
#define BLK     24
#define PSTR    516
#define LEAK_   0.1f
#define NTHR    1024
#define RSTR    520
#define NS      44               // per-thread gather slots (mean 25.6, sigma 3.4 -> +5.4 sigma)
#define LCAP    64               // prep list capacity per thread

// ---------------- fast-path LDS layout (hA/hB low so gather addr fits imm path) ----
#define F_HA_OFF     0                                  // 2048 B
#define F_HB_OFF     2048                               // 2048 B
#define F_RING_OFF   4096                               // 32*520*2 = 33280 B
#define F_PART_OFF   (F_RING_OFF + 32 * RSTR * 2)       // 37376
#define F_LDS_BYTES  (F_PART_OFF + BLK * PSTR * 4)      // 86912

// ---------------- workspace layout (bytes) ----------------
#define WS_WC        0
#define WS_WC_SZ     (5 * R_DIM * R_DIM * 2)            // 2,621,440
#define WS_POOL      (WS_WC + WS_WC_SZ)
#define WS_POOL_SZ   (NS * NTHR * 4)                    // 180,224
#define WS_LISTS     (WS_POOL + WS_POOL_SZ)
#define WS_LISTS_SZ  (NTHR * LCAP * 4)                  // 262,144
#define WS_CNT       (WS_LISTS + WS_LISTS_SZ)
#define WS_CNT_SZ    (NTHR * 4)
#define WS_TOTAL     (WS_CNT + WS_CNT_SZ)               // 3,067,904

// ---------------- fallback (round-1) LDS layout ----------------
#define CAP            26880
#define LDS_POOL_OFF   0
#define LDS_CPTR_OFF   (CAP * 4)
#define LDS_PART_OFF   (LDS_CPTR_OFF + 2052)
#define LDS_HA_OFF     (LDS_PART_OFF + BLK * PSTR * 4)
#define LDS_HB_OFF     (LDS_HA_OFF + R_DIM * 4)
#define LDS_BYTES_FB   (LDS_HB_OFF + R_DIM * 4)

typedef __attribute__((ext_vector_type(8))) short bf16x8;
typedef __attribute__((ext_vector_type(4))) float f32x4;

template <int N> struct IC { static constexpr int v = N; };

__device__ __forceinline__ unsigned f2bf(float f) {
  unsigned u = __float_as_uint(f);
  return (u + 0x7FFFu + ((u >> 16) & 1u)) >> 16;
}

__device__ __forceinline__ bf16x8 zero8() {
  bf16x8 a;
#pragma unroll
  for (int i = 0; i < 8; ++i) a[i] = 0;
  return a;
}

__device__ __forceinline__ bf16x8 load_afrag_g(const float* __restrict__ hbase,
                                               bool valid, int k0, int kb) {
  if (!valid) return zero8();
  const float4* p = (const float4*)(hbase + k0 + kb * 8);
  float4 v0 = p[0], v1 = p[1];
  bf16x8 a;
  a[0] = (short)f2bf(v0.x); a[1] = (short)f2bf(v0.y);
  a[2] = (short)f2bf(v0.z); a[3] = (short)f2bf(v0.w);
  a[4] = (short)f2bf(v1.x); a[5] = (short)f2bf(v1.y);
  a[6] = (short)f2bf(v1.z); a[7] = (short)f2bf(v1.w);
  return a;
}

__device__ __forceinline__ bf16x8 load_bfrag(const float* __restrict__ W,
                                             const unsigned short* __restrict__ Wc,
                                             int use_cache, int k0, int col, int kb) {
  bf16x8 b;
  if (use_cache) {
    const unsigned short* p = Wc + (size_t)col * R_DIM + k0 + kb * 8;
    b = *(const bf16x8*)p;
  } else {
    const float* p = W + (size_t)(k0 + kb * 8) * R_DIM + col;
#pragma unroll
    for (int i = 0; i < 8; ++i) b[i] = (short)f2bf(p[(size_t)i * R_DIM]);
  }
  return b;
}

// branchless tanh: 1 - 2/(exp2(2*log2e*a)+1); saturates correctly at +-inf args
__device__ __forceinline__ float fast_tanh(float a) {
  float e = __builtin_amdgcn_exp2f(a * 2.8853900817779268f);
  return 1.0f - 2.0f * __builtin_amdgcn_rcpf(e + 1.0f);
}

// ================= prep kernels =================
extern "C" __global__ void prep_wc(const float* __restrict__ Wfb,
                                   unsigned short* __restrict__ Wc) {
  int blk = blockIdx.x, r = threadIdx.x;
  int tap = blk >> 9, jc = blk & 511;
  float w = Wfb[((size_t)tap * R_DIM + r) * R_DIM + jc];
  Wc[((size_t)tap * R_DIM + jc) * R_DIM + r] = (unsigned short)f2bf(w);
}

extern "C" __global__ void prep_lists(const float* __restrict__ Wfb,
                                      unsigned* __restrict__ lists,
                                      unsigned* __restrict__ cnt) {
  int tid = threadIdx.x, j = tid >> 1, half = tid & 1;
  unsigned c = 0; int par = 0;
  for (int r = 0; r < R_DIM; ++r) {
    float w = Wfb[(size_t)r * R_DIM + j];
    if (w != 0.0f) {
      if ((par & 1) == half && c < LCAP)
        lists[(size_t)tid * LCAP + c++] = (f2bf(w) << 16) | (unsigned)(r * 4);
      ++par;
    }
  }
  cnt[tid] = c;
}

// greedy <=2-per-bank slot scheduler; pads ALL (slot,lane) positions to NS
extern "C" __global__ void prep_sched(const unsigned* __restrict__ lists,
                                      const unsigned* __restrict__ cnt,
                                      unsigned* __restrict__ pool) {
  __shared__ unsigned char L[16][NS][32];
  int w = threadIdx.x;
  if (w >= 16) return;
  for (int s = 0; s < NS; ++s)
    for (int b = 0; b < 32; ++b) L[w][s][b] = 0;
  for (int s = 0; s < NS; ++s)
    for (int lane = 0; lane < 64; ++lane)
      pool[s * NTHR + w * 64 + lane] = 0xFFFFFFFFu;
  for (int lane = 0; lane < 64; ++lane) {
    int tid = w * 64 + lane;
    unsigned c = cnt[tid]; if (c > NS) c = NS;
    unsigned long long used = 0ull;
    for (unsigned e = 0; e < c; ++e) {
      unsigned u = lists[(size_t)tid * LCAP + e];
      unsigned bank = (u >> 2) & 31u;
      int best = -1; unsigned bl = 255u;
      for (int s = 0; s < NS; ++s) {
        if ((used >> s) & 1ull) continue;
        unsigned ld = L[w][s][bank];
        if (ld < 2u) { best = s; break; }
        if (ld < bl) { bl = ld; best = s; }
      }
      pool[best * NTHR + tid] = u;
      used |= 1ull << best;
      L[w][best][bank]++;
    }
    for (int s = 0; s < NS; ++s) {
      if (pool[s * NTHR + tid] != 0xFFFFFFFFu) continue;
      unsigned bestb = 0, bl = 255u;
      for (int k = 0; k < 4; ++k) {
        unsigned b2 = (unsigned)((s * 7 + lane * 3 + k * 11) & 31);
        if (L[w][s][b2] < bl) { bl = L[w][s][b2]; bestb = b2; }
      }
      pool[s * NTHR + tid] = bestb * 4u;   // weight bits 0 -> harmless dummy
      L[w][s][bestb]++;
    }
  }
}

// ================= fast main kernel =================
extern "C" __global__ void __launch_bounds__(1024, 1)
reservoir_fast(const float* __restrict__ x, const float* __restrict__ Win,
               const float* __restrict__ Wfb, const float* __restrict__ bias,
               float* __restrict__ out, const unsigned short* __restrict__ Wc,
               const unsigned* __restrict__ pool) {
  extern __shared__ char lds[];
  unsigned short* ring = (unsigned short*)(lds + F_RING_OFF);
  float* partial = (float*)(lds + F_PART_OFF);

  const int b = blockIdx.x, tid = threadIdx.x;
  const int lane = tid & 63, wv = tid >> 6;
  float* outB = out + (size_t)b * S_LEN * R_DIM;
  const float* xB = x + (size_t)b * S_LEN * D_IN_;

  __builtin_amdgcn_fence(__ATOMIC_ACQUIRE, "agent");

  // init
  if (tid < R_DIM) {
    ((float*)(lds + F_HA_OFF))[tid] = 0.f;
    ((float*)(lds + F_HB_OFF))[tid] = 0.f;
  }
  for (int i = tid; i < 32 * RSTR; i += NTHR) ring[i] = 0;
  for (int i = tid; i < BLK * PSTR; i += NTHR) partial[i] = 0.f;
  __syncthreads();

  const int j = tid >> 1, half = tid & 1;
  float win_[D_IN_];
#pragma unroll
  for (int i = 0; i < D_IN_; ++i) win_[i] = Win[(size_t)j * D_IN_ + i];
  const float bj = bias[j];

  // hoist step-invariant gather entries into registers (fully unrolled use)
  unsigned ent[NS];
#pragma unroll
  for (int s = 0; s < NS; ++s) ent[s] = pool[(size_t)s * NTHR + tid];

  const int row16 = lane & 15, kb = lane >> 4;
  const int j0 = wv * 32;

  auto step = [&](auto OFSC, int t, int tm) {
    constexpr int OFS = decltype(OFSC)::v;   // read-buffer byte offset (0 or 2048)
    // -------- Phase A: tap-1 sparse gather from registers --------
    float a0 = 0.f, a1 = 0.f, a2 = 0.f, a3 = 0.f;
#pragma unroll
    for (int s = 0; s < NS; s += 4) {
      { unsigned u = ent[s + 0];
        a0 += __uint_as_float(u & 0xFFFF0000u) * *(const float*)(lds + OFS + (u & 2047u)); }
      { unsigned u = ent[s + 1];
        a1 += __uint_as_float(u & 0xFFFF0000u) * *(const float*)(lds + OFS + (u & 2047u)); }
      { unsigned u = ent[s + 2];
        a2 += __uint_as_float(u & 0xFFFF0000u) * *(const float*)(lds + OFS + (u & 2047u)); }
      { unsigned u = ent[s + 3];
        a3 += __uint_as_float(u & 0xFFFF0000u) * *(const float*)(lds + OFS + (u & 2047u)); }
    }
    float fb = (a0 + a1) + (a2 + a3);
    fb += __shfl_xor(fb, 1, 64);

    const float4* xp = (const float4*)(xB + (size_t)t * D_IN_);
    float4 x0 = xp[0], x1 = xp[1];
    float d = x0.x * win_[0] + x0.y * win_[1] + x0.z * win_[2] + x0.w * win_[3]
            + x1.x * win_[4] + x1.y * win_[5] + x1.z * win_[6] + x1.w * win_[7];
    float pa   = partial[tm * PSTR + j];
    float hold = *(const float*)(lds + OFS + j * 4);
    float aarg = fb + pa + d + bj;
    float hn = (1.0f - LEAK_) * hold + LEAK_ * fast_tanh(aarg);
    if (half == 0) {
      *(float*)(lds + (OFS ^ 2048) + j * 4) = hn;
      ring[(t & 31) * RSTR + j] = (unsigned short)f2bf(hn);
      outB[(size_t)t * R_DIM + j] = hn;
    }

    // single barrier per step: LDS-visible only (no vmcnt drain; outB stores
    // self-drain via in-order vmcnt long before the +96/+168 reads)
    __builtin_amdgcn_sched_barrier(0);
    asm volatile("s_waitcnt lgkmcnt(0)\n\ts_barrier" ::: "memory");
    __builtin_amdgcn_sched_barrier(0);

    if constexpr (OFS != 0) {   // B-phases only ever trigger on odd t
      const int tn = t + 1;
      // ---- B24: taps {24,96,168} for steps tn..tn+23 (overwrite partial; wave-local) ----
      if (tm == BLK - 1 && tn < S_LEN) {
        const int s0 = tn;
        f32x4 acc[2][2];
#pragma unroll
        for (int mt = 0; mt < 2; ++mt)
#pragma unroll
          for (int nt = 0; nt < 2; ++nt) acc[mt][nt] = (f32x4){0.f, 0.f, 0.f, 0.f};
        {
          const unsigned short* Wt = Wc + (size_t)2 * R_DIM * R_DIM;
#pragma unroll 1
          for (int k0 = 0; k0 < R_DIM; k0 += 32) {
            bf16x8 afr[2], bfr[2];
#pragma unroll
            for (int mt = 0; mt < 2; ++mt) {
              int srow = mt * 16 + row16;
              if (srow < BLK) {
                int rr = (s0 + srow - 24) & 31;
                afr[mt] = *(const bf16x8*)(ring + rr * RSTR + k0 + kb * 8);
              } else afr[mt] = zero8();
            }
#pragma unroll
            for (int nt = 0; nt < 2; ++nt)
              bfr[nt] = load_bfrag(nullptr, Wt, 1, k0, j0 + nt * 16 + row16, kb);
#pragma unroll
            for (int mt = 0; mt < 2; ++mt)
#pragma unroll
              for (int nt = 0; nt < 2; ++nt)
                acc[mt][nt] = __builtin_amdgcn_mfma_f32_16x16x32_bf16(
                    afr[mt], bfr[nt], acc[mt][nt], 0, 0, 0);
          }
        }
        const int taud[2] = {96, 168};
#pragma unroll 1
        for (int ti = 0; ti < 2; ++ti) {
          const int tau = taud[ti];
          const unsigned short* Wt = Wc + (size_t)(ti + 3) * R_DIM * R_DIM;
#pragma unroll 1
          for (int k0 = 0; k0 < R_DIM; k0 += 32) {
            bf16x8 afr[2], bfr[2];
#pragma unroll
            for (int mt = 0; mt < 2; ++mt) {
              int srow = mt * 16 + row16;
              int hs = s0 + srow - tau;
              bool v = (srow < BLK) && (hs >= 0);
              afr[mt] = load_afrag_g(outB + (size_t)(v ? hs : 0) * R_DIM, v, k0, kb);
            }
#pragma unroll
            for (int nt = 0; nt < 2; ++nt)
              bfr[nt] = load_bfrag(nullptr, Wt, 1, k0, j0 + nt * 16 + row16, kb);
#pragma unroll
            for (int mt = 0; mt < 2; ++mt)
#pragma unroll
              for (int nt = 0; nt < 2; ++nt)
                acc[mt][nt] = __builtin_amdgcn_mfma_f32_16x16x32_bf16(
                    afr[mt], bfr[nt], acc[mt][nt], 0, 0, 0);
          }
        }
#pragma unroll
        for (int mt = 0; mt < 2; ++mt)
#pragma unroll
          for (int q = 0; q < 4; ++q) {
            int srow = mt * 16 + kb * 4 + q;
            if (srow < BLK) {
#pragma unroll
              for (int nt = 0; nt < 2; ++nt)
                partial[srow * PSTR + j0 + nt * 16 + row16] = acc[mt][nt][q];
            }
          }
      }
      // ---- B4: tap {4} for steps tn..tn+3 (accumulate; wave-local) ----
      if ((t & 3) == 3 && tn < S_LEN) {
        const int s0 = tn;
        const int sb = (tm == BLK - 1) ? 0 : tm + 1;
        const unsigned short* Wt = Wc + (size_t)1 * R_DIM * R_DIM;
        f32x4 acc2[2];
        acc2[0] = (f32x4){0.f, 0.f, 0.f, 0.f};
        acc2[1] = (f32x4){0.f, 0.f, 0.f, 0.f};
#pragma unroll 1
        for (int k0 = 0; k0 < R_DIM; k0 += 32) {
          bf16x8 af;
          if (row16 < 4) {
            int rr = (s0 + row16 - 4) & 31;
            af = *(const bf16x8*)(ring + rr * RSTR + k0 + kb * 8);
          } else af = zero8();
#pragma unroll
          for (int nt = 0; nt < 2; ++nt) {
            bf16x8 bf_ = load_bfrag(nullptr, Wt, 1, k0, j0 + nt * 16 + row16, kb);
            acc2[nt] = __builtin_amdgcn_mfma_f32_16x16x32_bf16(af, bf_, acc2[nt], 0, 0, 0);
          }
        }
#pragma unroll
        for (int q = 0; q < 4; ++q) {
          int srow = kb * 4 + q;
          if (srow < 4) {
#pragma unroll
            for (int nt = 0; nt < 2; ++nt)
              partial[(sb + srow) * PSTR + j0 + nt * 16 + row16] += acc2[nt][q];
          }
        }
      }
    }
  };

  int tm = 0;
#pragma unroll 1
  for (int t = 0; t < S_LEN; t += 2) {
    step(IC<0>{}, t, tm);
    step(IC<2048>{}, t + 1, tm + 1);
    tm += 2; if (tm >= BLK) tm -= BLK;
  }
}

// ================= fallback (no/undersized workspace): round-1 kernel =================
extern "C" __global__ void __launch_bounds__(1024, 1)
reservoir_fb(const float* __restrict__ x, const float* __restrict__ Win,
             const float* __restrict__ Wfb, const float* __restrict__ bias,
             float* __restrict__ out, const unsigned short* __restrict__ Wc,
             int use_cache) {
  extern __shared__ char lds[];
  unsigned* pool   = (unsigned*)(lds + LDS_POOL_OFF);
  unsigned* colptr = (unsigned*)(lds + LDS_CPTR_OFF);
  float*    partial= (float*)(lds + LDS_PART_OFF);
  float*    hA     = (float*)(lds + LDS_HA_OFF);
  float*    hB     = (float*)(lds + LDS_HB_OFF);
  const int b = blockIdx.x, tid = threadIdx.x;
  const int lane = tid & 63, wv = tid >> 6;
  float* outB = out + (size_t)b * S_LEN * R_DIM;
  __builtin_amdgcn_fence(__ATOMIC_ACQUIRE, "agent");
  if (tid < R_DIM) {
    int c = 0;
    for (int r = 0; r < R_DIM; ++r) c += (Wfb[(size_t)r * R_DIM + tid] != 0.0f) ? 1 : 0;
    colptr[tid + 1] = (unsigned)c;
  }
  if (tid == 1023) colptr[0] = 0;
  __syncthreads();
  if (tid == 0) { unsigned run = 0; for (int i = 1; i <= R_DIM; ++i) { run += colptr[i]; colptr[i] = run; } }
  __syncthreads();
  if (tid < R_DIM) {
    unsigned p = colptr[tid];
    for (int r = 0; r < R_DIM; ++r) {
      float w = Wfb[(size_t)r * R_DIM + tid];
      if (w != 0.0f) { if (p < CAP) pool[p] = (f2bf(w) << 16) | (unsigned)r; ++p; }
    }
  }
  for (int i = tid; i < BLK * PSTR; i += 1024) partial[i] = 0.f;
  if (tid < R_DIM) { hA[tid] = 0.f; hB[tid] = 0.f; }
  __syncthreads();
  const int j = tid >> 1, half = tid & 1;
  float win_[D_IN_];
#pragma unroll
  for (int i = 0; i < D_IN_; ++i) win_[i] = Win[(size_t)j * D_IN_ + i];
  const float bj = bias[j];
  unsigned e0 = colptr[j], e1 = colptr[j + 1];
  unsigned mid = e0 + ((e1 - e0 + 1u) >> 1);
  unsigned gs = half ? mid : e0, ge = half ? e1 : mid;
  const int row16 = lane & 15, kb = lane >> 4, j0 = wv * 32;
  float* hprev = hA; float* hnext = hB; int tm = 0;
#pragma unroll 1
  for (int t = 0; t < S_LEN; ++t) {
    float fb = 0.f;
    for (unsigned e = gs; e < ge; ++e) {
      unsigned w = pool[e];
      fb += __uint_as_float(w & 0xFFFF0000u) * hprev[w & 511u];
    }
    fb += __shfl_xor(fb, 1, 64);
    if (half == 0) {
      const float* xp = x + ((size_t)b * S_LEN + t) * D_IN_;
      float d = 0.f;
#pragma unroll
      for (int i = 0; i < D_IN_; ++i) d += win_[i] * xp[i];
      float a = fb + partial[tm * PSTR + j] + d + bj;
      float hn = (1.0f - LEAK_) * hprev[j] + LEAK_ * tanhf(a);
      hnext[j] = hn;
      outB[(size_t)t * R_DIM + j] = hn;
    }
    __syncthreads();
    const int tn = t + 1;
    if ((tn & 3) == 0 && tn < S_LEN) {
      if (tm == BLK - 1) {
        const int s0 = tn;
        f32x4 acc[2][2];
#pragma unroll
        for (int mt = 0; mt < 2; ++mt)
#pragma unroll
          for (int nt = 0; nt < 2; ++nt) acc[mt][nt] = (f32x4){0.f, 0.f, 0.f, 0.f};
        const int taud[3] = {24, 96, 168};
#pragma unroll 1
        for (int ti = 0; ti < 3; ++ti) {
          const int tau = taud[ti];
          const float* W = Wfb + (size_t)(ti + 2) * R_DIM * R_DIM;
          const unsigned short* Wt = Wc + (size_t)(ti + 2) * R_DIM * R_DIM;
#pragma unroll 1
          for (int k0 = 0; k0 < R_DIM; k0 += 32) {
            bf16x8 afr[2], bfr[2];
#pragma unroll
            for (int mt = 0; mt < 2; ++mt) {
              int srow = mt * 16 + row16;
              int hs = s0 + srow - tau;
              bool v = (srow < BLK) && (hs >= 0);
              afr[mt] = load_afrag_g(outB + (size_t)(v ? hs : 0) * R_DIM, v, k0, kb);
            }
#pragma unroll
            for (int nt = 0; nt < 2; ++nt)
              bfr[nt] = load_bfrag(W, Wt, use_cache, k0, j0 + nt * 16 + row16, kb);
#pragma unroll
            for (int mt = 0; mt < 2; ++mt)
#pragma unroll
              for (int nt = 0; nt < 2; ++nt)
                acc[mt][nt] = __builtin_amdgcn_mfma_f32_16x16x32_bf16(afr[mt], bfr[nt], acc[mt][nt], 0, 0, 0);
          }
        }
#pragma unroll
        for (int mt = 0; mt < 2; ++mt)
#pragma unroll
          for (int q = 0; q < 4; ++q) {
            int srow = mt * 16 + kb * 4 + q;
            if (srow < BLK) {
#pragma unroll
              for (int nt = 0; nt < 2; ++nt)
                partial[srow * PSTR + j0 + nt * 16 + row16] = acc[mt][nt][q];
            }
          }
        __syncthreads();
      }
      {
        const int s0 = tn;
        const int sb = (tm == BLK - 1) ? 0 : tm + 1;
        const float* W = Wfb + (size_t)1 * R_DIM * R_DIM;
        const unsigned short* Wt = Wc + (size_t)1 * R_DIM * R_DIM;
        f32x4 acc2[2];
        acc2[0] = (f32x4){0.f, 0.f, 0.f, 0.f};
        acc2[1] = (f32x4){0.f, 0.f, 0.f, 0.f};
#pragma unroll 1
        for (int k0 = 0; k0 < R_DIM; k0 += 32) {
          int hs = s0 + row16 - 4;
          bool v = (row16 < 4);
          bf16x8 af = load_afrag_g(outB + (size_t)(v ? hs : 0) * R_DIM, v, k0, kb);
#pragma unroll
          for (int nt = 0; nt < 2; ++nt) {
            bf16x8 bf_ = load_bfrag(W, Wt, use_cache, k0, j0 + nt * 16 + row16, kb);
            acc2[nt] = __builtin_amdgcn_mfma_f32_16x16x32_bf16(af, bf_, acc2[nt], 0, 0, 0);
          }
        }
#pragma unroll
        for (int q = 0; q < 4; ++q) {
          int srow = kb * 4 + q;
          if (srow < 4) {
#pragma unroll
            for (int nt = 0; nt < 2; ++nt)
              partial[(sb + srow) * PSTR + j0 + nt * 16 + row16] += acc2[nt][q];
          }
        }
        __syncthreads();
      }
    }
    float* tsw = hprev; hprev = hnext; hnext = tsw;
    tm = (tm == BLK - 1) ? 0 : tm + 1;
  }
}

extern "C" void kernel_launch(void* const* d_in, const int* in_sizes, int n_in,
                              void* d_out, int out_size, void* d_ws, size_t ws_size,
                              hipStream_t stream) {
  const float* x    = (const float*)d_in[0];
  const float* Win  = (const float*)d_in[1];
  const float* Wfb  = (const float*)d_in[2];
  const float* bias = (const float*)d_in[3];
  float* out = (float*)d_out;
  char* ws = (char*)d_ws;

  if (d_ws != nullptr && ws_size >= (size_t)WS_TOTAL) {
    unsigned short* Wc = (unsigned short*)(ws + WS_WC);
    unsigned* pool  = (unsigned*)(ws + WS_POOL);
    unsigned* lists = (unsigned*)(ws + WS_LISTS);
    unsigned* cnt   = (unsigned*)(ws + WS_CNT);
    hipLaunchKernelGGL(prep_wc, dim3(5 * R_DIM), dim3(R_DIM), 0, stream, Wfb, Wc);
    hipLaunchKernelGGL(prep_lists, dim3(1), dim3(NTHR), 0, stream, Wfb, lists, cnt);
    hipLaunchKernelGGL(prep_sched, dim3(1), dim3(64), 0, stream, lists, cnt, pool);
    hipFuncSetAttribute((const void*)reservoir_fast,
                        hipFuncAttributeMaxDynamicSharedMemorySize, F_LDS_BYTES);
    hipLaunchKernelGGL(reservoir_fast, dim3(N_BATCH), dim3(NTHR), F_LDS_BYTES, stream,
                       x, Win, Wfb, bias, out, (const unsigned short*)Wc,
                       (const unsigned*)pool);
  } else {
    const size_t wc_bytes = (size_t)WS_WC_SZ;
    int use_cache = (d_ws != nullptr && ws_size >= wc_bytes) ? 1 : 0;
    unsigned short* Wc = use_cache ? (unsigned short*)d_ws : (unsigned short*)Wfb;
    if (use_cache)
      hipLaunchKernelGGL(prep_wc, dim3(5 * R_DIM), dim3(R_DIM), 0, stream, Wfb, Wc);
    hipFuncSetAttribute((const void*)reservoir_fb,
                        hipFuncAttributeMaxDynamicSharedMemorySize, LDS_BYTES_FB);
    hipLaunchKernelGGL(reservoir_fb, dim3(N_BATCH), dim3(NTHR), LDS_BYTES_FB, stream,
                       x, Win, Wfb, bias, out, (const unsigned short*)Wc, use_cache);
  }
}

// Round 4
// 42525.729 us; speedup vs baseline: 1.1145x; 1.1145x over previous
//
#include <hip/hip_runtime.h>

#define S_LEN   4096
#define R_DIM   512
#define N_BATCH 32
#define D_IN_   8
#define BLK     24
#define PSTR    516
#define LEAK_   0.1f
#define NTHR    1024
#define RSTR    520
#define NSCAP   44               // scheduler slot cap (worst lane ~37)
#define LCAP    63               // prep list capacity per thread

// ---------------- fast-path LDS layout ----------------
// [0, 8192): h quad-buffer: A-pri 0..2047, A-rep 2048..4095, B-pri 4096..6143, B-rep 6144..8191
#define F_HQ_BYTES   8192
#define F_RING_OFF   8192                               // 32*520*2 = 33280
#define F_PART_OFF   (F_RING_OFF + 32 * RSTR * 2)       // 41472
#define F_LDS_BYTES  (F_PART_OFF + BLK * PSTR * 4)      // 91008

// ---------------- workspace layout (bytes) ----------------
#define WS_WC        0
#define WS_WC_SZ     (5 * R_DIM * R_DIM * 2)            // 2,621,440
#define WS_POOL      (WS_WC + WS_WC_SZ)
#define WS_POOL_SZ   (NSCAP * NTHR * 4)                 // 180,224
#define WS_WNS       (WS_POOL + WS_POOL_SZ)
#define WS_WNS_SZ    64
#define WS_LISTS     (WS_WNS + WS_WNS_SZ)
#define WS_LISTS_SZ  (NTHR * LCAP * 4)                  // 258,048
#define WS_CNT       (WS_LISTS + WS_LISTS_SZ)
#define WS_CNT_SZ    4096
#define WS_TOTAL     (WS_CNT + WS_CNT_SZ)               // 3,063,872 (< proven 3,067,904)

// ---------------- fallback (round-1) LDS layout ----------------
#define CAP            26880
#define LDS_POOL_OFF   0
#define LDS_CPTR_OFF   (CAP * 4)
#define LDS_PART_OFF   (LDS_CPTR_OFF + 2052)
#define LDS_HA_OFF     (LDS_PART_OFF + BLK * PSTR * 4)
#define LDS_HB_OFF     (LDS_HA_OFF + R_DIM * 4)
#define LDS_BYTES_FB   (LDS_HB_OFF + R_DIM * 4)

typedef __attribute__((ext_vector_type(8))) short bf16x8;
typedef __attribute__((ext_vector_type(4))) float f32x4;

template <int N> struct IC { static constexpr int v = N; };

__device__ __forceinline__ unsigned f2bf(float f) {
  unsigned u = __float_as_uint(f);
  return (u + 0x7FFFu + ((u >> 16) & 1u)) >> 16;
}

__device__ __forceinline__ bf16x8 zero8() {
  bf16x8 a;
#pragma unroll
  for (int i = 0; i < 8; ++i) a[i] = 0;
  return a;
}

__device__ __forceinline__ bf16x8 load_afrag_g(const float* __restrict__ hbase,
                                               bool valid, int k0, int kb) {
  if (!valid) return zero8();
  const float4* p = (const float4*)(hbase + k0 + kb * 8);
  float4 v0 = p[0], v1 = p[1];
  bf16x8 a;
  a[0] = (short)f2bf(v0.x); a[1] = (short)f2bf(v0.y);
  a[2] = (short)f2bf(v0.z); a[3] = (short)f2bf(v0.w);
  a[4] = (short)f2bf(v1.x); a[5] = (short)f2bf(v1.y);
  a[6] = (short)f2bf(v1.z); a[7] = (short)f2bf(v1.w);
  return a;
}

__device__ __forceinline__ bf16x8 load_bfrag(const float* __restrict__ W,
                                             const unsigned short* __restrict__ Wc,
                                             int use_cache, int k0, int col, int kb) {
  bf16x8 b;
  if (use_cache) {
    const unsigned short* p = Wc + (size_t)col * R_DIM + k0 + kb * 8;
    b = *(const bf16x8*)p;
  } else {
    const float* p = W + (size_t)(k0 + kb * 8) * R_DIM + col;
#pragma unroll
    for (int i = 0; i < 8; ++i) b[i] = (short)f2bf(p[(size_t)i * R_DIM]);
  }
  return b;
}

__device__ __forceinline__ float fast_tanh(float a) {
  float e = __builtin_amdgcn_exp2f(a * 2.8853900817779268f);
  return 1.0f - 2.0f * __builtin_amdgcn_rcpf(e + 1.0f);
}

// ================= prep kernels =================
extern "C" __global__ void prep_wc(const float* __restrict__ Wfb,
                                   unsigned short* __restrict__ Wc) {
  int blk = blockIdx.x, r = threadIdx.x;
  int tap = blk >> 9, jc = blk & 511;
  float w = Wfb[((size_t)tap * R_DIM + r) * R_DIM + jc];
  Wc[((size_t)tap * R_DIM + jc) * R_DIM + r] = (unsigned short)f2bf(w);
}

// per-thread compact nonzero list of W_fb[0] column (parity-split across pair); raw r index
extern "C" __global__ void prep_lists(const float* __restrict__ Wfb,
                                      unsigned* __restrict__ lists,
                                      unsigned* __restrict__ cnt) {
  int tid = threadIdx.x, j = tid >> 1, half = tid & 1;
  unsigned c = 0; int par = 0;
  for (int r = 0; r < R_DIM; ++r) {
    float w = Wfb[(size_t)r * R_DIM + j];
    if (w != 0.0f) {
      if ((par & 1) == half && c < LCAP)
        lists[(size_t)tid * LCAP + c++] = (f2bf(w) << 16) | (unsigned)r;
      ++par;
    }
  }
  cnt[tid] = c;
}

// 2-home (+17 bank replica) per-half-wave <=1-per-bank scheduler; one thread per wave.
// Entry word: (bf16 weight << 16) | byte-addr in [0,4096) (primary [0,2048) / replica [2048,4096)).
extern "C" __global__ void prep_sched2(const unsigned* __restrict__ lists,
                                       const unsigned* __restrict__ cnt,
                                       unsigned* __restrict__ pool,
                                       unsigned* __restrict__ wns) {
  __shared__ unsigned char used[16][NSCAP][2][32];
  int w = threadIdx.x;
  if (w >= 16) return;
  for (int s = 0; s < NSCAP; ++s)
    for (int hw = 0; hw < 2; ++hw)
      for (int b = 0; b < 32; ++b) used[w][s][hw][b] = 0;
  for (int s = 0; s < NSCAP; ++s)
    for (int l = 0; l < 64; ++l) pool[s * NTHR + w * 64 + l] = 0xFFFFFFFFu;
  int maxs = 4;
  for (int l = 0; l < 64; ++l) {
    int tid = w * 64 + l, hw = l >> 5;
    unsigned c = cnt[tid]; if (c > NSCAP) c = NSCAP;
    unsigned long long lu = 0ull;
    for (unsigned e = 0; e < c; ++e) {
      unsigned u = lists[(size_t)tid * LCAP + e];
      unsigned r = u & 511u;
      unsigned b0 = r & 31u, b1 = (r + 17u) & 31u;
      unsigned a0 = r * 4u;
      unsigned a1 = 2048u + (((r & ~31u) | ((r + 17u) & 31u)) << 2);
      int best = -1; unsigned ba = 0;
      for (int s = 0; s < NSCAP; ++s) {
        if ((lu >> s) & 1ull) continue;
        if (!used[w][s][hw][b0]) { best = s; ba = a0; used[w][s][hw][b0] = 1; break; }
        if (!used[w][s][hw][b1]) { best = s; ba = a1; used[w][s][hw][b1] = 1; break; }
      }
      if (best < 0) {  // perf-only fallback: least-loaded home on a lane-free slot
        unsigned bl = 255u; int bs = -1; int bh = 0;
        for (int s = 0; s < NSCAP; ++s) {
          if ((lu >> s) & 1ull) continue;
          if (used[w][s][hw][b0] < bl) { bl = used[w][s][hw][b0]; bs = s; bh = 0; }
          if (used[w][s][hw][b1] < bl) { bl = used[w][s][hw][b1]; bs = s; bh = 1; }
        }
        if (bs < 0) continue;                        // cannot happen (c <= NSCAP)
        best = bs; ba = bh ? a1 : a0;
        used[w][best][hw][bh ? b1 : b0]++;
      }
      pool[best * NTHR + tid] = (u & 0xFFFF0000u) | ba;
      lu |= 1ull << best;
      if (best + 1 > maxs) maxs = best + 1;
    }
  }
  int ns = (maxs + 3) & ~3; if (ns > NSCAP) ns = NSCAP;
  wns[w] = (unsigned)ns;
  for (int l = 0; l < 64; ++l) {
    int tid = w * 64 + l, hw = l >> 5;
    for (int s = 0; s < ns; ++s) {
      if (pool[s * NTHR + tid] != 0xFFFFFFFFu) continue;
      unsigned bb = 0, bl = 255u;
      for (int b = 0; b < 32; ++b)
        if (used[w][s][hw][b] < bl) { bl = used[w][s][hw][b]; bb = b; }
      used[w][s][hw][bb]++;
      pool[s * NTHR + tid] = bb * 4u;               // weight 0 dummy, primary region
    }
  }
}

// ================= fast main kernel =================
#define GSTEP(u, acc) \
  { acc += __uint_as_float((u) & 0xFFFF0000u) * \
           *(const float*)(lds + OFS + ((u) & 4095u)); }

extern "C" __global__ void __launch_bounds__(1024, 1)
reservoir_fast(const float* __restrict__ x, const float* __restrict__ Win,
               const float* __restrict__ Wfb, const float* __restrict__ bias,
               float* __restrict__ out, const unsigned short* __restrict__ Wc,
               const unsigned* __restrict__ pool, const unsigned* __restrict__ wns) {
  extern __shared__ char lds[];
  unsigned short* ring = (unsigned short*)(lds + F_RING_OFF);
  float* partial = (float*)(lds + F_PART_OFF);

  const int b = blockIdx.x, tid = threadIdx.x;
  const int lane = tid & 63, wv = tid >> 6;
  float* outB = out + (size_t)b * S_LEN * R_DIM;
  const float* xB = x + (size_t)b * S_LEN * D_IN_;

  __builtin_amdgcn_fence(__ATOMIC_ACQUIRE, "agent");

  // init: h quad-buffer, ring, partial
  for (int i = tid; i < F_HQ_BYTES / 4; i += NTHR) ((float*)lds)[i] = 0.f;
  for (int i = tid; i < 32 * RSTR; i += NTHR) ring[i] = 0;
  for (int i = tid; i < BLK * PSTR; i += NTHR) partial[i] = 0.f;
  __syncthreads();

  const int j = tid >> 1, half = tid & 1;
  float win_[D_IN_];
#pragma unroll
  for (int i = 0; i < D_IN_; ++i) win_[i] = Win[(size_t)j * D_IN_ + i];
  const float bj = bias[j];
  const unsigned ns = __builtin_amdgcn_readfirstlane(wns[wv]);  // multiple of 4
  const unsigned* poolT = pool + tid;

  // replica byte offset for this thread's h[j] write: bank (j+17)&31 within j's 32-word row
  const unsigned repoff = 2048u + ((((unsigned)j & ~31u) | (((unsigned)j + 17u) & 31u)) << 2);

  const int row16 = lane & 15, kb = lane >> 4;
  const int j0 = wv * 32;

  auto step = [&](auto OFSC, int t, int tm) {
    constexpr int OFS = decltype(OFSC)::v;   // read-buffer base (0 or 4096)
    // -------- Phase A: tap-1 sparse gather (bank-perfect scheduled, pool from L2) --------
    float a0 = 0.f, a1 = 0.f, a2 = 0.f, a3 = 0.f;
    unsigned c0 = poolT[0], c1 = poolT[NTHR], c2 = poolT[2 * NTHR], c3 = poolT[3 * NTHR];
#pragma unroll 1
    for (unsigned s = 4; s < ns; s += 4) {
      unsigned n0 = poolT[(s + 0) * NTHR], n1 = poolT[(s + 1) * NTHR];
      unsigned n2 = poolT[(s + 2) * NTHR], n3 = poolT[(s + 3) * NTHR];
      GSTEP(c0, a0); GSTEP(c1, a1); GSTEP(c2, a2); GSTEP(c3, a3);
      c0 = n0; c1 = n1; c2 = n2; c3 = n3;
    }
    GSTEP(c0, a0); GSTEP(c1, a1); GSTEP(c2, a2); GSTEP(c3, a3);

    float fb = (a0 + a1) + (a2 + a3);
    fb += __shfl_xor(fb, 1, 64);

    const float4* xp = (const float4*)(xB + (size_t)t * D_IN_);
    float4 x0 = xp[0], x1 = xp[1];
    float d = x0.x * win_[0] + x0.y * win_[1] + x0.z * win_[2] + x0.w * win_[3]
            + x1.x * win_[4] + x1.y * win_[5] + x1.z * win_[6] + x1.w * win_[7];
    float pa   = partial[tm * PSTR + j];
    float hold = *(const float*)(lds + OFS + j * 4);
    float aarg = fb + pa + d + bj;
    float hn = (1.0f - LEAK_) * hold + LEAK_ * fast_tanh(aarg);
    if (half == 0) {
      *(float*)(lds + (OFS ^ 4096) + j * 4)   = hn;   // primary (1/bank across wave)
      *(float*)(lds + (OFS ^ 4096) + repoff)  = hn;   // +17-bank replica (1/bank)
      ring[(t & 31) * RSTR + j] = (unsigned short)f2bf(hn);
      outB[(size_t)t * R_DIM + j] = hn;
    }

    __builtin_amdgcn_sched_barrier(0);
    asm volatile("s_waitcnt lgkmcnt(0)\n\ts_barrier" ::: "memory");
    __builtin_amdgcn_sched_barrier(0);

    if constexpr (OFS != 0) {   // B-phases trigger only on odd t
      const int tn = t + 1;
      // ---- B24: taps {24,96,168} for steps tn..tn+23 (overwrite partial; wave-local) ----
      if (tm == BLK - 1 && tn < S_LEN) {
        const int s0 = tn;
        f32x4 acc[2][2];
#pragma unroll
        for (int mt = 0; mt < 2; ++mt)
#pragma unroll
          for (int nt = 0; nt < 2; ++nt) acc[mt][nt] = (f32x4){0.f, 0.f, 0.f, 0.f};
        {
          const unsigned short* Wt = Wc + (size_t)2 * R_DIM * R_DIM;
#pragma unroll 1
          for (int k0 = 0; k0 < R_DIM; k0 += 32) {
            bf16x8 afr[2], bfr[2];
#pragma unroll
            for (int mt = 0; mt < 2; ++mt) {
              int srow = mt * 16 + row16;
              if (srow < BLK) {
                int rr = (s0 + srow - 24) & 31;
                afr[mt] = *(const bf16x8*)(ring + rr * RSTR + k0 + kb * 8);
              } else afr[mt] = zero8();
            }
#pragma unroll
            for (int nt = 0; nt < 2; ++nt)
              bfr[nt] = load_bfrag(nullptr, Wt, 1, k0, j0 + nt * 16 + row16, kb);
#pragma unroll
            for (int mt = 0; mt < 2; ++mt)
#pragma unroll
              for (int nt = 0; nt < 2; ++nt)
                acc[mt][nt] = __builtin_amdgcn_mfma_f32_16x16x32_bf16(
                    afr[mt], bfr[nt], acc[mt][nt], 0, 0, 0);
          }
        }
        const int taud[2] = {96, 168};
#pragma unroll 1
        for (int ti = 0; ti < 2; ++ti) {
          const int tau = taud[ti];
          const unsigned short* Wt = Wc + (size_t)(ti + 3) * R_DIM * R_DIM;
#pragma unroll 1
          for (int k0 = 0; k0 < R_DIM; k0 += 32) {
            bf16x8 afr[2], bfr[2];
#pragma unroll
            for (int mt = 0; mt < 2; ++mt) {
              int srow = mt * 16 + row16;
              int hs = s0 + srow - tau;
              bool v = (srow < BLK) && (hs >= 0);
              afr[mt] = load_afrag_g(outB + (size_t)(v ? hs : 0) * R_DIM, v, k0, kb);
            }
#pragma unroll
            for (int nt = 0; nt < 2; ++nt)
              bfr[nt] = load_bfrag(nullptr, Wt, 1, k0, j0 + nt * 16 + row16, kb);
#pragma unroll
            for (int mt = 0; mt < 2; ++mt)
#pragma unroll
              for (int nt = 0; nt < 2; ++nt)
                acc[mt][nt] = __builtin_amdgcn_mfma_f32_16x16x32_bf16(
                    afr[mt], bfr[nt], acc[mt][nt], 0, 0, 0);
          }
        }
#pragma unroll
        for (int mt = 0; mt < 2; ++mt)
#pragma unroll
          for (int q = 0; q < 4; ++q) {
            int srow = mt * 16 + kb * 4 + q;
            if (srow < BLK) {
#pragma unroll
              for (int nt = 0; nt < 2; ++nt)
                partial[srow * PSTR + j0 + nt * 16 + row16] = acc[mt][nt][q];
            }
          }
      }
      // ---- B4: tap {4} for steps tn..tn+3 (accumulate; wave-local) ----
      if ((t & 3) == 3 && tn < S_LEN) {
        const int s0 = tn;
        const int sb = (tm == BLK - 1) ? 0 : tm + 1;
        const unsigned short* Wt = Wc + (size_t)1 * R_DIM * R_DIM;
        f32x4 acc2[2];
        acc2[0] = (f32x4){0.f, 0.f, 0.f, 0.f};
        acc2[1] = (f32x4){0.f, 0.f, 0.f, 0.f};
#pragma unroll 1
        for (int k0 = 0; k0 < R_DIM; k0 += 32) {
          bf16x8 af;
          if (row16 < 4) {
            int rr = (s0 + row16 - 4) & 31;
            af = *(const bf16x8*)(ring + rr * RSTR + k0 + kb * 8);
          } else af = zero8();
#pragma unroll
          for (int nt = 0; nt < 2; ++nt) {
            bf16x8 bf_ = load_bfrag(nullptr, Wt, 1, k0, j0 + nt * 16 + row16, kb);
            acc2[nt] = __builtin_amdgcn_mfma_f32_16x16x32_bf16(af, bf_, acc2[nt], 0, 0, 0);
          }
        }
#pragma unroll
        for (int q = 0; q < 4; ++q) {
          int srow = kb * 4 + q;
          if (srow < 4) {
#pragma unroll
            for (int nt = 0; nt < 2; ++nt)
              partial[(sb + srow) * PSTR + j0 + nt * 16 + row16] += acc2[nt][q];
          }
        }
      }
    }
  };

  int tm = 0;
#pragma unroll 1
  for (int t = 0; t < S_LEN; t += 2) {
    step(IC<0>{}, t, tm);
    step(IC<4096>{}, t + 1, tm + 1);
    tm += 2; if (tm >= BLK) tm -= BLK;
  }
}

// ================= fallback (no/undersized workspace): round-1 kernel =================
extern "C" __global__ void __launch_bounds__(1024, 1)
reservoir_fb(const float* __restrict__ x, const float* __restrict__ Win,
             const float* __restrict__ Wfb, const float* __restrict__ bias,
             float* __restrict__ out, const unsigned short* __restrict__ Wc,
             int use_cache) {
  extern __shared__ char lds[];
  unsigned* pool   = (unsigned*)(lds + LDS_POOL_OFF);
  unsigned* colptr = (unsigned*)(lds + LDS_CPTR_OFF);
  float*    partial= (float*)(lds + LDS_PART_OFF);
  float*    hA     = (float*)(lds + LDS_HA_OFF);
  float*    hB     = (float*)(lds + LDS_HB_OFF);
  const int b = blockIdx.x, tid = threadIdx.x;
  const int lane = tid & 63, wv = tid >> 6;
  float* outB = out + (size_t)b * S_LEN * R_DIM;
  __builtin_amdgcn_fence(__ATOMIC_ACQUIRE, "agent");
  if (tid < R_DIM) {
    int c = 0;
    for (int r = 0; r < R_DIM; ++r) c += (Wfb[(size_t)r * R_DIM + tid] != 0.0f) ? 1 : 0;
    colptr[tid + 1] = (unsigned)c;
  }
  if (tid == 1023) colptr[0] = 0;
  __syncthreads();
  if (tid == 0) { unsigned run = 0; for (int i = 1; i <= R_DIM; ++i) { run += colptr[i]; colptr[i] = run; } }
  __syncthreads();
  if (tid < R_DIM) {
    unsigned p = colptr[tid];
    for (int r = 0; r < R_DIM; ++r) {
      float w = Wfb[(size_t)r * R_DIM + tid];
      if (w != 0.0f) { if (p < CAP) pool[p] = (f2bf(w) << 16) | (unsigned)r; ++p; }
    }
  }
  for (int i = tid; i < BLK * PSTR; i += 1024) partial[i] = 0.f;
  if (tid < R_DIM) { hA[tid] = 0.f; hB[tid] = 0.f; }
  __syncthreads();
  const int j = tid >> 1, half = tid & 1;
  float win_[D_IN_];
#pragma unroll
  for (int i = 0; i < D_IN_; ++i) win_[i] = Win[(size_t)j * D_IN_ + i];
  const float bj = bias[j];
  unsigned e0 = colptr[j], e1 = colptr[j + 1];
  unsigned mid = e0 + ((e1 - e0 + 1u) >> 1);
  unsigned gs = half ? mid : e0, ge = half ? e1 : mid;
  const int row16 = lane & 15, kb = lane >> 4, j0 = wv * 32;
  float* hprev = hA; float* hnext = hB; int tm = 0;
#pragma unroll 1
  for (int t = 0; t < S_LEN; ++t) {
    float fb = 0.f;
    for (unsigned e = gs; e < ge; ++e) {
      unsigned w = pool[e];
      fb += __uint_as_float(w & 0xFFFF0000u) * hprev[w & 511u];
    }
    fb += __shfl_xor(fb, 1, 64);
    if (half == 0) {
      const float* xp = x + ((size_t)b * S_LEN + t) * D_IN_;
      float d = 0.f;
#pragma unroll
      for (int i = 0; i < D_IN_; ++i) d += win_[i] * xp[i];
      float a = fb + partial[tm * PSTR + j] + d + bj;
      float hn = (1.0f - LEAK_) * hprev[j] + LEAK_ * tanhf(a);
      hnext[j] = hn;
      outB[(size_t)t * R_DIM + j] = hn;
    }
    __syncthreads();
    const int tn = t + 1;
    if ((tn & 3) == 0 && tn < S_LEN) {
      if (tm == BLK - 1) {
        const int s0 = tn;
        f32x4 acc[2][2];
#pragma unroll
        for (int mt = 0; mt < 2; ++mt)
#pragma unroll
          for (int nt = 0; nt < 2; ++nt) acc[mt][nt] = (f32x4){0.f, 0.f, 0.f, 0.f};
        const int taud[3] = {24, 96, 168};
#pragma unroll 1
        for (int ti = 0; ti < 3; ++ti) {
          const int tau = taud[ti];
          const float* W = Wfb + (size_t)(ti + 2) * R_DIM * R_DIM;
          const unsigned short* Wt = Wc + (size_t)(ti + 2) * R_DIM * R_DIM;
#pragma unroll 1
          for (int k0 = 0; k0 < R_DIM; k0 += 32) {
            bf16x8 afr[2], bfr[2];
#pragma unroll
            for (int mt = 0; mt < 2; ++mt) {
              int srow = mt * 16 + row16;
              int hs = s0 + srow - tau;
              bool v = (srow < BLK) && (hs >= 0);
              afr[mt] = load_afrag_g(outB + (size_t)(v ? hs : 0) * R_DIM, v, k0, kb);
            }
#pragma unroll
            for (int nt = 0; nt < 2; ++nt)
              bfr[nt] = load_bfrag(W, Wt, use_cache, k0, j0 + nt * 16 + row16, kb);
#pragma unroll
            for (int mt = 0; mt < 2; ++mt)
#pragma unroll
              for (int nt = 0; nt < 2; ++nt)
                acc[mt][nt] = __builtin_amdgcn_mfma_f32_16x16x32_bf16(afr[mt], bfr[nt], acc[mt][nt], 0, 0, 0);
          }
        }
#pragma unroll
        for (int mt = 0; mt < 2; ++mt)
#pragma unroll
          for (int q = 0; q < 4; ++q) {
            int srow = mt * 16 + kb * 4 + q;
            if (srow < BLK) {
#pragma unroll
              for (int nt = 0; nt < 2; ++nt)
                partial[srow * PSTR + j0 + nt * 16 + row16] = acc[mt][nt][q];
            }
          }
        __syncthreads();
      }
      {
        const int s0 = tn;
        const int sb = (tm == BLK - 1) ? 0 : tm + 1;
        const float* W = Wfb + (size_t)1 * R_DIM * R_DIM;
        const unsigned short* Wt = Wc + (size_t)1 * R_DIM * R_DIM;
        f32x4 acc2[2];
        acc2[0] = (f32x4){0.f, 0.f, 0.f, 0.f};
        acc2[1] = (f32x4){0.f, 0.f, 0.f, 0.f};
#pragma unroll 1
        for (int k0 = 0; k0 < R_DIM; k0 += 32) {
          int hs = s0 + row16 - 4;
          bool v = (row16 < 4);
          bf16x8 af = load_afrag_g(outB + (size_t)(v ? hs : 0) * R_DIM, v, k0, kb);
#pragma unroll
          for (int nt = 0; nt < 2; ++nt) {
            bf16x8 bf_ = load_bfrag(W, Wt, use_cache, k0, j0 + nt * 16 + row16, kb);
            acc2[nt] = __builtin_amdgcn_mfma_f32_16x16x32_bf16(af, bf_, acc2[nt], 0, 0, 0);
          }
        }
#pragma unroll
        for (int q = 0; q < 4; ++q) {
          int srow = kb * 4 + q;
          if (srow < 4) {
#pragma unroll
            for (int nt = 0; nt < 2; ++nt)
              partial[(sb + srow) * PSTR + j0 + nt * 16 + row16] += acc2[nt][q];
          }
        }
        __syncthreads();
      }
    }
    float* tsw = hprev; hprev = hnext; hnext = tsw;
    tm = (tm == BLK - 1) ? 0 : tm + 1;
  }
}

extern "C" void kernel_launch(void* const* d_in, const int* in_sizes, int n_in,
                              void* d_out, int out_size, void* d_ws, size_t ws_size,
                              hipStream_t stream) {
  const float* x    = (const float*)d_in[0];
  const float* Win  = (const float*)d_in[1];
  const float* Wfb  = (const float*)d_in[2];
  const float* bias = (const float*)d_in[3];
  float* out = (float*)d_out;
  char* ws = (char*)d_ws;

  if (d_ws != nullptr && ws_size >= (size_t)WS_TOTAL) {
    unsigned short* Wc = (unsigned short*)(ws + WS_WC);
    unsigned* pool  = (unsigned*)(ws + WS_POOL);
    unsigned* wnsp  = (unsigned*)(ws + WS_WNS);
    unsigned* lists = (unsigned*)(ws + WS_LISTS);
    unsigned* cnt   = (unsigned*)(ws + WS_CNT);
    hipLaunchKernelGGL(prep_wc, dim3(5 * R_DIM), dim3(R_DIM), 0, stream, Wfb, Wc);
    hipLaunchKernelGGL(prep_lists, dim3(1), dim3(NTHR), 0, stream, Wfb, lists, cnt);
    hipLaunchKernelGGL(prep_sched2, dim3(1), dim3(64), 0, stream, lists, cnt, pool, wnsp);
    hipFuncSetAttribute((const void*)reservoir_fast,
                        hipFuncAttributeMaxDynamicSharedMemorySize, F_LDS_BYTES);
    hipLaunchKernelGGL(reservoir_fast, dim3(N_BATCH), dim3(NTHR), F_LDS_BYTES, stream,
                       x, Win, Wfb, bias, out, (const unsigned short*)Wc,
                       (const unsigned*)pool, (const unsigned*)wnsp);
  } else {
    const size_t wc_bytes = (size_t)WS_WC_SZ;
    int use_cache = (d_ws != nullptr && ws_size >= wc_bytes) ? 1 : 0;
    unsigned short* Wc = use_cache ? (unsigned short*)d_ws : (unsigned short*)Wfb;
    if (use_cache)
      hipLaunchKernelGGL(prep_wc, dim3(5 * R_DIM), dim3(R_DIM), 0, stream, Wfb, Wc);
    hipFuncSetAttribute((const void*)reservoir_fb,
                        hipFuncAttributeMaxDynamicSharedMemorySize, LDS_BYTES_FB);
    hipLaunchKernelGGL(reservoir_fb, dim3(N_BATCH), dim3(NTHR), LDS_BYTES_FB, stream,
                       x, Win, Wfb, bias, out, (const unsigned short*)Wc, use_cache);
  }
}